// Round 2
// baseline (7686.285 us; speedup 1.0000x reference)
//
#include <hip/hip_runtime.h>
#include <cstdint>

// Bidirectional masked LSTM encoder, B=64, T=512, E=256, U=512, G=2048.
// Design: single persistent kernel does BOTH the input projection (emb@W) and
// the recurrence (h@U) with bf16 MFMA (16x16x32). 64 WGs = 32 per direction;
// each WG owns 16 units (64 gate-cols) and holds its U-slice (128 VGPR) and
// W-slice (64 VGPR) in registers for all 512 steps. Per-step cross-WG handoff
// of h goes through a global ping-pong buffer + per-direction arrival counters
// (device-scope atomics, __threadfence for wbl2/inv across XCD L2s).
//
// R1 fix: H reader strides were 2x the [cg][b][16u] element layout
// ((k0>>4)*2048 + b*32 -> (k0>>4)*1024 + b*16) — recurrence read garbage.

#define B_ 64
#define T_ 512
#define E_ 256

typedef __attribute__((ext_vector_type(8))) short bf16x8;
typedef __attribute__((ext_vector_type(4))) float f32x4;

__device__ __forceinline__ unsigned short f2bf(float x) {
  unsigned u = __float_as_uint(x);
  u += 0x7FFFu + ((u >> 16) & 1u);      // round-to-nearest-even
  return (unsigned short)(u >> 16);
}
__device__ __forceinline__ float sigm(float x) { return 1.0f / (1.0f + __expf(-x)); }
__device__ __forceinline__ float tanh_(float x) { return 1.0f - 2.0f / (__expf(2.0f * x) + 1.0f); }

// Gather + f32->bf16 cast of the embedded sequence into [t][b][e] layout.
__global__ void prep_kernel(const int* __restrict__ enc, const float* __restrict__ emb,
                            unsigned short* __restrict__ o) {
  const int bi = blockIdx.x;
  const int t = bi >> 6, b = bi & 63;
  const int tok = enc[b * T_ + t];
  float4 v = ((const float4*)(emb + (size_t)tok * E_))[threadIdx.x];
  ushort4 w;
  w.x = f2bf(v.x); w.y = f2bf(v.y); w.z = f2bf(v.z); w.w = f2bf(v.w);
  ((ushort4*)(o + (size_t)t * (B_ * E_) + b * E_))[threadIdx.x] = w;
}

// 64 blocks x 256 threads. block = (dir d, col-group cg): units [cg*16, cg*16+16).
// Wave (of 4) = (mh, nh): 32x32 output quadrant of the WG's 64 batch x 64 gate-col tile.
__global__ __launch_bounds__(256, 1)
void lstm_kernel(const int* __restrict__ enc, const unsigned short* __restrict__ embq,
                 const float* __restrict__ Wf, const float* __restrict__ Uf, const float* __restrict__ bfv,
                 const float* __restrict__ Wb, const float* __restrict__ Ub, const float* __restrict__ bbv,
                 unsigned short* __restrict__ Hbuf, unsigned* __restrict__ cnt,
                 float* __restrict__ out) {
  const int tid = threadIdx.x;
  const int lane = tid & 63;
  const int wave = tid >> 6;
  const int mh = wave & 1, nh = wave >> 1;
  const int l15 = lane & 15, l4 = lane >> 4;
  const int d = blockIdx.x >> 5;
  const int cg = blockIdx.x & 31;
  const int u0 = cg * 16;
  const float* Wd = d ? Wb : Wf;
  const float* Ud = d ? Ub : Uf;
  const float* bd = d ? bbv : bfv;

  __shared__ float Z[64][68];   // gate-regroup exchange, +4 pad vs 64 to spread banks

  // ---- recurrent weights U -> registers as MFMA B-frags (B[k=quad*8+j][n=lane&15]) ----
  bf16x8 u_frag[16][2];
#pragma unroll
  for (int ks = 0; ks < 16; ++ks) {
#pragma unroll
    for (int ns = 0; ns < 2; ++ns) {
      const int gate = nh * 2 + ns;
      const int col = gate * 512 + u0 + l15;
      const int k0 = ks * 32 + l4 * 8;
      bf16x8 f;
#pragma unroll
      for (int i = 0; i < 8; ++i) f[i] = (short)f2bf(Ud[(size_t)(k0 + i) * 2048 + col]);
      u_frag[ks][ns] = f;
    }
  }
  // ---- input-projection weights W -> registers ----
  bf16x8 w_frag[8][2];
#pragma unroll
  for (int ks = 0; ks < 8; ++ks) {
#pragma unroll
    for (int ns = 0; ns < 2; ++ns) {
      const int gate = nh * 2 + ns;
      const int col = gate * 512 + u0 + l15;
      const int k0 = ks * 32 + l4 * 8;
      bf16x8 f;
#pragma unroll
      for (int i = 0; i < 8; ++i) f[i] = (short)f2bf(Wd[(size_t)(k0 + i) * 2048 + col]);
      w_frag[ks][ns] = f;
    }
  }

  // epilogue assignment: thread -> (unit j = tid&15, batches b = (tid>>4)*4 + r)
  const int ej = tid & 15;
  const int ebg = tid >> 4;
  float bias[4];
#pragma unroll
  for (int g = 0; g < 4; ++g) bias[g] = bd[g * 512 + u0 + ej];

  float hst[4] = {0.f, 0.f, 0.f, 0.f}, cst[4] = {0.f, 0.f, 0.f, 0.f};

  // prefetch emb A-frags for step 0 (A[m=lane&15][k=quad*8+j])
  bf16x8 apf[8][2];
  {
    const int t0 = d ? 511 : 0;
    const unsigned short* eT = embq + (size_t)t0 * (B_ * E_);
#pragma unroll
    for (int ks = 0; ks < 8; ++ks)
#pragma unroll
      for (int ms = 0; ms < 2; ++ms) {
        const int b = mh * 32 + ms * 16 + l15;
        const int e0 = ks * 32 + l4 * 8;
        apf[ks][ms] = *(const bf16x8*)(eT + b * E_ + e0);
      }
  }

  unsigned* cntd = cnt + d * 513;

  for (int s = 0; s < 512; ++s) {
    const int t = d ? (511 - s) : s;
    f32x4 acc[2][2];
#pragma unroll
    for (int ms = 0; ms < 2; ++ms)
#pragma unroll
      for (int ns = 0; ns < 2; ++ns) acc[ms][ns] = (f32x4)0.0f;

    // ---- x-part: emb @ W (no dependence on other WGs: runs BEFORE the spin) ----
#pragma unroll
    for (int ks = 0; ks < 8; ++ks)
#pragma unroll
      for (int ms = 0; ms < 2; ++ms)
#pragma unroll
        for (int ns = 0; ns < 2; ++ns)
          acc[ms][ns] = __builtin_amdgcn_mfma_f32_16x16x32_bf16(apf[ks][ms], w_frag[ks][ns],
                                                                acc[ms][ns], 0, 0, 0);

    // ---- wait for all 32 WGs of this direction to have published h(s) ----
    if (s > 0 && tid == 0) {
      while (__hip_atomic_load(cntd + s, __ATOMIC_RELAXED, __HIP_MEMORY_SCOPE_AGENT) < 32u)
        __builtin_amdgcn_s_sleep(2);
    }
    __syncthreads();
    __threadfence();   // acquire side: invalidate stale L1/L2 before reading H

    // ---- h-part: H @ U, A-frags streamed from global (L2/L3), software-pipelined ----
    // H layout: [cg][b][16u] elements -> unit k0+i lives at (k0>>4)*1024 + b*16 + (k0&15)+i
    {
      const unsigned short* Hrd = Hbuf + ((size_t)((s & 1) * 2 + d)) * 32768;
      bf16x8 ap[8];
#pragma unroll
      for (int p = 0; p < 8; ++p) {
        const int ks = p >> 1, ms = p & 1;
        const int b = mh * 32 + ms * 16 + l15;
        const int k0 = ks * 32 + l4 * 8;
        ap[p] = *(const bf16x8*)(Hrd + (k0 >> 4) * 1024 + b * 16 + (k0 & 15));
      }
#pragma unroll
      for (int fl = 0; fl < 32; ++fl) {
        const int ks = fl >> 1, ms = fl & 1;
        bf16x8 a = ap[fl & 7];
        if (fl + 8 < 32) {
          const int f2i = fl + 8;
          const int ks2 = f2i >> 1, ms2 = f2i & 1;
          const int b = mh * 32 + ms2 * 16 + l15;
          const int k0 = ks2 * 32 + l4 * 8;
          ap[fl & 7] = *(const bf16x8*)(Hrd + (k0 >> 4) * 1024 + b * 16 + (k0 & 15));
        }
        acc[ms][0] = __builtin_amdgcn_mfma_f32_16x16x32_bf16(a, u_frag[ks][0], acc[ms][0], 0, 0, 0);
        acc[ms][1] = __builtin_amdgcn_mfma_f32_16x16x32_bf16(a, u_frag[ks][1], acc[ms][1], 0, 0, 0);
      }
    }

    // ---- regroup gates per (b,u) via LDS (C/D layout: col=lane&15, row=quad*4+reg) ----
#pragma unroll
    for (int ms = 0; ms < 2; ++ms)
#pragma unroll
      for (int ns = 0; ns < 2; ++ns)
#pragma unroll
        for (int r = 0; r < 4; ++r)
          Z[mh * 32 + ms * 16 + l4 * 4 + r][nh * 32 + ns * 16 + l15] = acc[ms][ns][r];
    __syncthreads();

    // ---- elementwise LSTM cell + masked carry + stores ----
    {
      unsigned short* Hwr = Hbuf + ((size_t)(((s + 1) & 1) * 2 + d)) * 32768 + cg * 1024;
      const bool last = (s == 511);
#pragma unroll
      for (int r = 0; r < 4; ++r) {
        const int b = ebg * 4 + r;
        float zi = Z[b][ej] + bias[0];
        float zf = Z[b][16 + ej] + bias[1];
        float zg = Z[b][32 + ej] + bias[2];
        float zo = Z[b][48 + ej] + bias[3];
        float ig = sigm(zi), fg = sigm(zf), gg = tanh_(zg), og = sigm(zo);
        float cn = fg * cst[r] + ig * gg;
        float hn = og * tanh_(cn);
        const bool m = (enc[b * T_ + t] != 0);
        cst[r] = m ? cn : cst[r];
        hst[r] = m ? hn : hst[r];
        out[((size_t)b * T_ + t) * 1024 + d * 512 + u0 + ej] = hst[r];
        Hwr[b * 16 + ej] = f2bf(hst[r]);
        if (last) {
          out[33554432u + (size_t)b * 1024 + d * 512 + u0 + ej] = hst[r];
          out[33619968u + (size_t)b * 1024 + d * 512 + u0 + ej] = cst[r];
        }
      }
    }

    // ---- prefetch emb A-frags for step s+1 (hidden under fence/spin latency) ----
    if (s < 511) {
      const int tn = d ? (510 - s) : (s + 1);
      const unsigned short* eT = embq + (size_t)tn * (B_ * E_);
#pragma unroll
      for (int ks = 0; ks < 8; ++ks)
#pragma unroll
        for (int ms = 0; ms < 2; ++ms) {
          const int b = mh * 32 + ms * 16 + l15;
          const int e0 = ks * 32 + l4 * 8;
          apf[ks][ms] = *(const bf16x8*)(eT + b * E_ + e0);
        }
    }

    __threadfence();   // release side: drain stores + wbl2 so other XCDs can see h
    __syncthreads();
    if (tid == 0)
      __hip_atomic_fetch_add(cntd + (s + 1), 1u, __ATOMIC_RELAXED, __HIP_MEMORY_SCOPE_AGENT);
  }
}

extern "C" void kernel_launch(void* const* d_in, const int* in_sizes, int n_in,
                              void* d_out, int out_size, void* d_ws, size_t ws_size,
                              hipStream_t stream) {
  const int* enc = (const int*)d_in[0];
  const float* emb = (const float*)d_in[1];
  const float* Wf = (const float*)d_in[2];
  const float* Uf = (const float*)d_in[3];
  const float* bf = (const float*)d_in[4];
  const float* Wb = (const float*)d_in[5];
  const float* Ub = (const float*)d_in[6];
  const float* bb = (const float*)d_in[7];
  float* out = (float*)d_out;
  char* ws = (char*)d_ws;

  unsigned short* embq = (unsigned short*)ws;                    // [T][B][E] bf16, 16 MiB
  unsigned short* Hbuf = (unsigned short*)(ws + (16u << 20));    // [2][2][32cg][64b][16u] bf16, 256 KiB
  unsigned* cnt = (unsigned*)(ws + (16u << 20) + 262144u);       // [2][513] arrival counters

  // ws is re-poisoned to 0xAA before every timed launch: zero H ping-pong + counters.
  hipMemsetAsync(ws + (16u << 20), 0, 262144u + 4104u, stream);
  prep_kernel<<<32768, 64, 0, stream>>>(enc, emb, embq);
  lstm_kernel<<<64, 256, 0, stream>>>(enc, embq, Wf, Uf, bf, Wb, Ub, bb, Hbuf, cnt, out);
}

// Round 3
// 3425.836 us; speedup vs baseline: 2.2436x; 2.2436x over previous
//
#include <hip/hip_runtime.h>
#include <cstdint>

// Bidirectional masked LSTM encoder, B=64, T=512, E=256, U=512, G=2048.
// Persistent kernel: 64 WGs = 32 per direction; each WG owns 16 units
// (64 gate-cols), U-slice (128 VGPR) + W-slice (64 VGPR) resident in regs.
// R3: cross-WG h handoff via sc0 sc1 (LLC-coherent) loads/stores ONLY —
// no __threadfence (R2's buffer_wbl2/buffer_inv flushed the whole XCD L2
// every step: 360 MB HBM fetch, 14.7 us/step latency-bound).

#define B_ 64
#define T_ 512
#define E_ 256

typedef __attribute__((ext_vector_type(8))) short bf16x8;
typedef __attribute__((ext_vector_type(4))) float f32x4;

__device__ __forceinline__ unsigned short f2bf(float x) {
  unsigned u = __float_as_uint(x);
  u += 0x7FFFu + ((u >> 16) & 1u);      // round-to-nearest-even
  return (unsigned short)(u >> 16);
}
__device__ __forceinline__ float sigm(float x) { return 1.0f / (1.0f + __expf(-x)); }
__device__ __forceinline__ float tanh_(float x) { return 1.0f - 2.0f / (__expf(2.0f * x) + 1.0f); }

// Gather + f32->bf16 cast of the embedded sequence into [t][b][e] layout.
__global__ void prep_kernel(const int* __restrict__ enc, const float* __restrict__ emb,
                            unsigned short* __restrict__ o) {
  const int bi = blockIdx.x;
  const int t = bi >> 6, b = bi & 63;
  const int tok = enc[b * T_ + t];
  float4 v = ((const float4*)(emb + (size_t)tok * E_))[threadIdx.x];
  ushort4 w;
  w.x = f2bf(v.x); w.y = f2bf(v.y); w.z = f2bf(v.z); w.w = f2bf(v.w);
  ((ushort4*)(o + (size_t)t * (B_ * E_) + b * E_))[threadIdx.x] = w;
}

// 64 blocks x 256 threads. block = (dir d, col-group cg): units [cg*16, cg*16+16).
// Wave (of 4) = (mh, nh): 32x32 output quadrant of the WG's 64 batch x 64 gate-col tile.
__global__ __launch_bounds__(256, 1)
void lstm_kernel(const int* __restrict__ enc, const unsigned short* __restrict__ embq,
                 const float* __restrict__ Wf, const float* __restrict__ Uf, const float* __restrict__ bfv,
                 const float* __restrict__ Wb, const float* __restrict__ Ub, const float* __restrict__ bbv,
                 unsigned short* __restrict__ Hbuf, unsigned* __restrict__ cnt,
                 float* __restrict__ out) {
  const int tid = threadIdx.x;
  const int lane = tid & 63;
  const int wave = tid >> 6;
  const int mh = wave & 1, nh = wave >> 1;
  const int l15 = lane & 15, l4 = lane >> 4;
  const int d = blockIdx.x >> 5;
  const int cg = blockIdx.x & 31;
  const int u0 = cg * 16;
  const float* Wd = d ? Wb : Wf;
  const float* Ud = d ? Ub : Uf;
  const float* bd = d ? bbv : bfv;

  __shared__ float Z[64][68];   // gate-regroup exchange, +4 pad to spread banks

  // ---- recurrent weights U -> registers as MFMA B-frags (B[k=quad*8+j][n=lane&15]) ----
  bf16x8 u_frag[16][2];
#pragma unroll
  for (int ks = 0; ks < 16; ++ks) {
#pragma unroll
    for (int ns = 0; ns < 2; ++ns) {
      const int gate = nh * 2 + ns;
      const int col = gate * 512 + u0 + l15;
      const int k0 = ks * 32 + l4 * 8;
      bf16x8 f;
#pragma unroll
      for (int i = 0; i < 8; ++i) f[i] = (short)f2bf(Ud[(size_t)(k0 + i) * 2048 + col]);
      u_frag[ks][ns] = f;
    }
  }
  // ---- input-projection weights W -> registers ----
  bf16x8 w_frag[8][2];
#pragma unroll
  for (int ks = 0; ks < 8; ++ks) {
#pragma unroll
    for (int ns = 0; ns < 2; ++ns) {
      const int gate = nh * 2 + ns;
      const int col = gate * 512 + u0 + l15;
      const int k0 = ks * 32 + l4 * 8;
      bf16x8 f;
#pragma unroll
      for (int i = 0; i < 8; ++i) f[i] = (short)f2bf(Wd[(size_t)(k0 + i) * 2048 + col]);
      w_frag[ks][ns] = f;
    }
  }

  // epilogue assignment: thread -> (unit j = tid&15, batches b = (tid>>4)*4 + r)
  const int ej = tid & 15;
  const int ebg = tid >> 4;
  float bias[4];
#pragma unroll
  for (int g = 0; g < 4; ++g) bias[g] = bd[g * 512 + u0 + ej];

  float hst[4] = {0.f, 0.f, 0.f, 0.f}, cst[4] = {0.f, 0.f, 0.f, 0.f};

  // prefetch emb A-frags + mask for step 0 (A[m=lane&15][k=quad*8+j])
  bf16x8 apf[8][2];
  int mpf[4];
  {
    const int t0 = d ? 511 : 0;
    const unsigned short* eT = embq + (size_t)t0 * (B_ * E_);
#pragma unroll
    for (int ks = 0; ks < 8; ++ks)
#pragma unroll
      for (int ms = 0; ms < 2; ++ms) {
        const int b = mh * 32 + ms * 16 + l15;
        const int e0 = ks * 32 + l4 * 8;
        apf[ks][ms] = *(const bf16x8*)(eT + b * E_ + e0);
      }
#pragma unroll
    for (int r = 0; r < 4; ++r) mpf[r] = enc[(ebg * 4 + r) * T_ + t0];
  }

  unsigned* cntd = cnt + d * 513;

  for (int s = 0; s < 512; ++s) {
    const int t = d ? (511 - s) : s;
    f32x4 acc[2][2];
#pragma unroll
    for (int ms = 0; ms < 2; ++ms)
#pragma unroll
      for (int ns = 0; ns < 2; ++ns) acc[ms][ns] = (f32x4)0.0f;

    // ---- x-part: emb @ W (independent of other WGs: runs BEFORE the spin) ----
#pragma unroll
    for (int ks = 0; ks < 8; ++ks)
#pragma unroll
      for (int ms = 0; ms < 2; ++ms)
#pragma unroll
        for (int ns = 0; ns < 2; ++ns)
          acc[ms][ns] = __builtin_amdgcn_mfma_f32_16x16x32_bf16(apf[ks][ms], w_frag[ks][ns],
                                                                acc[ms][ns], 0, 0, 0);

    if (s > 0) {
      // ---- wait for all 32 WGs of this direction to have published h(s) ----
      if (tid == 0) {
        while (__hip_atomic_load(cntd + s, __ATOMIC_RELAXED, __HIP_MEMORY_SCOPE_AGENT) < 32u) {}
      }
      __syncthreads();

      // ---- h-part: H @ U. A-frags via LLC-coherent loads (sc0 sc1), one asm
      //      block: 32x global_load_dwordx4 issued back-to-back, single wait.
      // H layout [cg][b][16u] elems; frag(ks,ms) byte off = ks*4096 + ms*512 +
      //   (l4>>1)*2048 + mh*1024 + l15*32 + (l4&1)*16
      bf16x8 ha[16][2];
      {
        const unsigned short* Hrd = Hbuf + ((size_t)((s & 1) * 2 + d)) * 32768;
        const char* lb = (const char*)Hrd + (l4 >> 1) * 2048 + mh * 1024 + l15 * 32 + (l4 & 1) * 16;
        const char* b0p = lb + 0 * 8192 + 4096;
        const char* b1p = lb + 1 * 8192 + 4096;
        const char* b2p = lb + 2 * 8192 + 4096;
        const char* b3p = lb + 3 * 8192 + 4096;
        const char* b4p = lb + 4 * 8192 + 4096;
        const char* b5p = lb + 5 * 8192 + 4096;
        const char* b6p = lb + 6 * 8192 + 4096;
        const char* b7p = lb + 7 * 8192 + 4096;
        asm volatile(
          "global_load_dwordx4 %0, %32, off offset:-4096 sc0 sc1\n\t"
          "global_load_dwordx4 %1, %32, off offset:-3584 sc0 sc1\n\t"
          "global_load_dwordx4 %2, %32, off offset:0 sc0 sc1\n\t"
          "global_load_dwordx4 %3, %32, off offset:512 sc0 sc1\n\t"
          "global_load_dwordx4 %4, %33, off offset:-4096 sc0 sc1\n\t"
          "global_load_dwordx4 %5, %33, off offset:-3584 sc0 sc1\n\t"
          "global_load_dwordx4 %6, %33, off offset:0 sc0 sc1\n\t"
          "global_load_dwordx4 %7, %33, off offset:512 sc0 sc1\n\t"
          "global_load_dwordx4 %8, %34, off offset:-4096 sc0 sc1\n\t"
          "global_load_dwordx4 %9, %34, off offset:-3584 sc0 sc1\n\t"
          "global_load_dwordx4 %10, %34, off offset:0 sc0 sc1\n\t"
          "global_load_dwordx4 %11, %34, off offset:512 sc0 sc1\n\t"
          "global_load_dwordx4 %12, %35, off offset:-4096 sc0 sc1\n\t"
          "global_load_dwordx4 %13, %35, off offset:-3584 sc0 sc1\n\t"
          "global_load_dwordx4 %14, %35, off offset:0 sc0 sc1\n\t"
          "global_load_dwordx4 %15, %35, off offset:512 sc0 sc1\n\t"
          "global_load_dwordx4 %16, %36, off offset:-4096 sc0 sc1\n\t"
          "global_load_dwordx4 %17, %36, off offset:-3584 sc0 sc1\n\t"
          "global_load_dwordx4 %18, %36, off offset:0 sc0 sc1\n\t"
          "global_load_dwordx4 %19, %36, off offset:512 sc0 sc1\n\t"
          "global_load_dwordx4 %20, %37, off offset:-4096 sc0 sc1\n\t"
          "global_load_dwordx4 %21, %37, off offset:-3584 sc0 sc1\n\t"
          "global_load_dwordx4 %22, %37, off offset:0 sc0 sc1\n\t"
          "global_load_dwordx4 %23, %37, off offset:512 sc0 sc1\n\t"
          "global_load_dwordx4 %24, %38, off offset:-4096 sc0 sc1\n\t"
          "global_load_dwordx4 %25, %38, off offset:-3584 sc0 sc1\n\t"
          "global_load_dwordx4 %26, %38, off offset:0 sc0 sc1\n\t"
          "global_load_dwordx4 %27, %38, off offset:512 sc0 sc1\n\t"
          "global_load_dwordx4 %28, %39, off offset:-4096 sc0 sc1\n\t"
          "global_load_dwordx4 %29, %39, off offset:-3584 sc0 sc1\n\t"
          "global_load_dwordx4 %30, %39, off offset:0 sc0 sc1\n\t"
          "global_load_dwordx4 %31, %39, off offset:512 sc0 sc1\n\t"
          "s_waitcnt vmcnt(0)"
          : "=v"(ha[0][0]), "=v"(ha[0][1]), "=v"(ha[1][0]), "=v"(ha[1][1]),
            "=v"(ha[2][0]), "=v"(ha[2][1]), "=v"(ha[3][0]), "=v"(ha[3][1]),
            "=v"(ha[4][0]), "=v"(ha[4][1]), "=v"(ha[5][0]), "=v"(ha[5][1]),
            "=v"(ha[6][0]), "=v"(ha[6][1]), "=v"(ha[7][0]), "=v"(ha[7][1]),
            "=v"(ha[8][0]), "=v"(ha[8][1]), "=v"(ha[9][0]), "=v"(ha[9][1]),
            "=v"(ha[10][0]), "=v"(ha[10][1]), "=v"(ha[11][0]), "=v"(ha[11][1]),
            "=v"(ha[12][0]), "=v"(ha[12][1]), "=v"(ha[13][0]), "=v"(ha[13][1]),
            "=v"(ha[14][0]), "=v"(ha[14][1]), "=v"(ha[15][0]), "=v"(ha[15][1])
          : "v"(b0p), "v"(b1p), "v"(b2p), "v"(b3p),
            "v"(b4p), "v"(b5p), "v"(b6p), "v"(b7p)
          : "memory");
      }
#pragma unroll
      for (int ks = 0; ks < 16; ++ks) {
        acc[0][0] = __builtin_amdgcn_mfma_f32_16x16x32_bf16(ha[ks][0], u_frag[ks][0], acc[0][0], 0, 0, 0);
        acc[0][1] = __builtin_amdgcn_mfma_f32_16x16x32_bf16(ha[ks][0], u_frag[ks][1], acc[0][1], 0, 0, 0);
        acc[1][0] = __builtin_amdgcn_mfma_f32_16x16x32_bf16(ha[ks][1], u_frag[ks][0], acc[1][0], 0, 0, 0);
        acc[1][1] = __builtin_amdgcn_mfma_f32_16x16x32_bf16(ha[ks][1], u_frag[ks][1], acc[1][1], 0, 0, 0);
      }
    } else {
      __syncthreads();   // keep barrier count uniform-ish (h==0 at s=0)
    }

    // ---- regroup gates per (b,u) via LDS (C/D layout: col=lane&15, row=quad*4+reg) ----
#pragma unroll
    for (int ms = 0; ms < 2; ++ms)
#pragma unroll
      for (int ns = 0; ns < 2; ++ns)
#pragma unroll
        for (int r = 0; r < 4; ++r)
          Z[mh * 32 + ms * 16 + l4 * 4 + r][nh * 32 + ns * 16 + l15] = acc[ms][ns][r];
    __syncthreads();

    // ---- elementwise LSTM cell + masked carry + stores ----
    unsigned hu[4];
    {
      const bool last = (s == 511);
#pragma unroll
      for (int r = 0; r < 4; ++r) {
        const int b = ebg * 4 + r;
        float zi = Z[b][ej] + bias[0];
        float zf = Z[b][16 + ej] + bias[1];
        float zg = Z[b][32 + ej] + bias[2];
        float zo = Z[b][48 + ej] + bias[3];
        float ig = sigm(zi), fg = sigm(zf), gg = tanh_(zg), og = sigm(zo);
        float cn = fg * cst[r] + ig * gg;
        float hn = og * tanh_(cn);
        const bool m = (mpf[r] != 0);
        cst[r] = m ? cn : cst[r];
        hst[r] = m ? hn : hst[r];
        hu[r] = (unsigned)f2bf(hst[r]);
        out[((size_t)b * T_ + t) * 1024 + d * 512 + u0 + ej] = hst[r];
        if (last) {
          out[33554432u + (size_t)b * 1024 + d * 512 + u0 + ej] = hst[r];
          out[33619968u + (size_t)b * 1024 + d * 512 + u0 + ej] = cst[r];
        }
      }
    }

    // ---- prefetch emb A-frags + mask for step s+1 (normal loads, overlap) ----
    if (s < 511) {
      const int tn = d ? (510 - s) : (s + 1);
      const unsigned short* eT = embq + (size_t)tn * (B_ * E_);
#pragma unroll
      for (int ks = 0; ks < 8; ++ks)
#pragma unroll
        for (int ms = 0; ms < 2; ++ms) {
          const int b = mh * 32 + ms * 16 + l15;
          const int e0 = ks * 32 + l4 * 8;
          apf[ks][ms] = *(const bf16x8*)(eT + b * E_ + e0);
        }
#pragma unroll
      for (int r = 0; r < 4; ++r) mpf[r] = enc[(ebg * 4 + r) * T_ + tn];
    }

    // ---- publish h(s+1): LLC write-through stores, drain, barrier, flag ----
    {
      unsigned short* Hwr = Hbuf + ((size_t)(((s + 1) & 1) * 2 + d)) * 32768 + cg * 1024;
      char* hp = (char*)(Hwr + ebg * 64 + ej);
      asm volatile(
        "global_store_short %0, %1, off sc0 sc1\n\t"
        "global_store_short %0, %2, off offset:32 sc0 sc1\n\t"
        "global_store_short %0, %3, off offset:64 sc0 sc1\n\t"
        "global_store_short %0, %4, off offset:96 sc0 sc1\n\t"
        "s_waitcnt vmcnt(0)"
        :: "v"(hp), "v"(hu[0]), "v"(hu[1]), "v"(hu[2]), "v"(hu[3])
        : "memory");
    }
    __syncthreads();
    if (tid == 0)
      __hip_atomic_fetch_add(cntd + (s + 1), 1u, __ATOMIC_RELAXED, __HIP_MEMORY_SCOPE_AGENT);
  }
}

extern "C" void kernel_launch(void* const* d_in, const int* in_sizes, int n_in,
                              void* d_out, int out_size, void* d_ws, size_t ws_size,
                              hipStream_t stream) {
  const int* enc = (const int*)d_in[0];
  const float* emb = (const float*)d_in[1];
  const float* Wf = (const float*)d_in[2];
  const float* Uf = (const float*)d_in[3];
  const float* bf = (const float*)d_in[4];
  const float* Wb = (const float*)d_in[5];
  const float* Ub = (const float*)d_in[6];
  const float* bb = (const float*)d_in[7];
  float* out = (float*)d_out;
  char* ws = (char*)d_ws;

  unsigned short* embq = (unsigned short*)ws;                    // [T][B][E] bf16, 16 MiB
  unsigned short* Hbuf = (unsigned short*)(ws + (16u << 20));    // [2][2][32cg][64b][16u] bf16, 256 KiB
  unsigned* cnt = (unsigned*)(ws + (16u << 20) + 262144u);       // [2][513] arrival counters

  // Only the counters need zeroing (h==0 path at s=0 never reads Hbuf).
  hipMemsetAsync(ws + (16u << 20) + 262144u, 0, 4104u, stream);
  prep_kernel<<<32768, 64, 0, stream>>>(enc, emb, embq);
  lstm_kernel<<<64, 256, 0, stream>>>(enc, embq, Wf, Uf, bf, Wb, Ub, bb, Hbuf, cnt, out);
}